// Round 4
// baseline (437.310 us; speedup 1.0000x reference)
//
#include <hip/hip_runtime.h>

// out[b,t,u] = y[b,t]*out[b,t-1,u] + x[b,t]*z[b,t,u], out[b,-1,u]=0
// in layout: [B][T][F], F=1026: x=col0, y=col1, z=cols 2..1025
//
// Single-pass chunked scan with decoupled look-back (aggregate-only):
//  - virtual block id from atomic counter => spin only on already-resident blocks
//  - phase 1: zero-init recurrence over CC rows, out1[t] kept in REGISTERS,
//             publish (A = prod y, B[u] = out1[last]) with release flag
//  - phase 2: fold predecessors' (A_j, B_j) -> carry (L2/L3 resident, ~2 MB)
//  - phase 3: out[t] = out1[t] + q_t, q_t = y_t*q_{t-1}, q_{-1}=carry  (no re-read)
// Input read ONCE from HBM, output written once => ~268 MB fabric traffic.

#define BB 8
#define TT 4096
#define FF 1026
#define UU 1024
#define NC 64
#define CC 64               // TT/NC
#define NBLK (BB * NC * 2)  // 1024 blocks, 512 units each, 2 units/thread

typedef float f2 __attribute__((ext_vector_type(2)));

__global__ __launch_bounds__(256) void k_lookback(const float* __restrict__ in,
                                                  float* __restrict__ out,
                                                  int* __restrict__ flags,   // [NBLK]
                                                  int* __restrict__ counter, // [1]
                                                  float* __restrict__ Agg,   // [NBLK]
                                                  float* __restrict__ Bc) {  // [NBLK][512]
    __shared__ int s_vid;
    __shared__ float s_y[CC];
    if (threadIdx.x == 0) s_vid = atomicAdd(counter, 1);
    __syncthreads();
    const int vid = s_vid;
    const int c   = vid >> 4;      // chunk (major => predecessors have smaller vid)
    const int r   = vid & 15;
    const int b   = r >> 1;
    const int us  = r & 1;
    const int u   = us * 512 + threadIdx.x * 2;

    const float* xyp = in + ((size_t)b * TT + (size_t)c * CC) * FF;
    const float* zp  = xyp + 2 + u;

    // ---- phase 1: local zero-init scan, state in registers ----
    float o1x[CC], o1y[CC];
    float accx = 0.f, accy = 0.f, yprod = 1.f;
#pragma unroll
    for (int t = 0; t < CC; ++t) {
        f2 xy = *reinterpret_cast<const f2*>(xyp + (size_t)t * FF);
        f2 z  = *reinterpret_cast<const f2*>(zp  + (size_t)t * FF);
        accx = fmaf(xy.y, accx, xy.x * z.x);
        accy = fmaf(xy.y, accy, xy.x * z.y);
        o1x[t] = accx; o1y[t] = accy;
        yprod *= xy.y;
        if (threadIdx.x == 0) s_y[t] = xy.y;
    }

    // ---- publish aggregate (release) ----
    {
        f2 o; o.x = accx; o.y = accy;
        *reinterpret_cast<f2*>(Bc + (size_t)vid * 512 + threadIdx.x * 2) = o;
        if (threadIdx.x == 0) Agg[vid] = yprod;
    }
    __threadfence();   // make B/A visible device-wide before flag
    __syncthreads();   // all threads' writes done before thread0 flags
    if (threadIdx.x == 0)
        __hip_atomic_store(&flags[vid], 1, __ATOMIC_RELEASE, __HIP_MEMORY_SCOPE_AGENT);

    // ---- phase 2: look-back over predecessors (same b, us) ----
    float cx = 0.f, cy = 0.f;
    if (c > 0) {
        const int base = b * 2 + us;           // pred flag index = j*16 + base
        if (threadIdx.x == 0) {
            for (int j = 0; j < c; ++j)
                while (__hip_atomic_load(&flags[j * 16 + base], __ATOMIC_ACQUIRE,
                                         __HIP_MEMORY_SCOPE_AGENT) == 0)
                    __builtin_amdgcn_s_sleep(2);
        }
        __syncthreads();
        for (int j = 0; j < c; ++j) {
            const int fj = j * 16 + base;
            float a = Agg[fj];
            f2 bv = *reinterpret_cast<const f2*>(Bc + (size_t)fj * 512 + threadIdx.x * 2);
            cx = fmaf(a, cx, bv.x);
            cy = fmaf(a, cy, bv.y);
        }
    }

    // ---- phase 3: apply carry, stream out (no input re-read) ----
    float* orow = out + ((size_t)b * TT + (size_t)c * CC) * UU + u;
#pragma unroll
    for (int t = 0; t < CC; ++t) {
        float yt = s_y[t];
        cx *= yt; cy *= yt;
        f2 o; o.x = o1x[t] + cx; o.y = o1y[t] + cy;
        __builtin_nontemporal_store(o, reinterpret_cast<f2*>(orow + (size_t)t * UU));
    }
}

// ---------------- fallback (round-2 structure) if ws too small ----------------
__global__ __launch_bounds__(256) void k_partial32(const float* __restrict__ in,
                                                   float* __restrict__ A,
                                                   float* __restrict__ Bc) {
    int bid = blockIdx.x, s = bid & 1, chunk = (bid >> 1) & 31, b = bid >> 6;
    int u = s * 512 + threadIdx.x * 2;
    const float* row = in + ((size_t)b * TT + (size_t)chunk * 128) * FF;
    float accx = 0.f, accy = 0.f, yprod = 1.f;
#pragma unroll 8
    for (int t = 0; t < 128; ++t) {
        f2 xy = *reinterpret_cast<const f2*>(row + (size_t)t * FF);
        f2 z  = *reinterpret_cast<const f2*>(row + (size_t)t * FF + 2 + u);
        accx = fmaf(xy.y, accx, xy.x * z.x);
        accy = fmaf(xy.y, accy, xy.x * z.y);
        yprod *= xy.y;
    }
    f2 o; o.x = accx; o.y = accy;
    *reinterpret_cast<f2*>(Bc + ((size_t)b * 32 + chunk) * UU + u) = o;
    if (threadIdx.x == 0 && s == 0) A[b * 32 + chunk] = yprod;
}
__global__ __launch_bounds__(256) void k_scan32(const float* __restrict__ A,
                                                float* __restrict__ Bc) {
    int tid = blockIdx.x * 256 + threadIdx.x;
    int b = tid / 512, u = (tid % 512) * 2;
    float cx = 0.f, cy = 0.f;
#pragma unroll
    for (int c = 0; c < 32; ++c) {
        float a = A[b * 32 + c];
        f2* p = reinterpret_cast<f2*>(Bc + ((size_t)b * 32 + c) * UU + u);
        f2 bv = *p;
        cx = fmaf(a, cx, bv.x); cy = fmaf(a, cy, bv.y);
        f2 o; o.x = cx; o.y = cy; *p = o;
    }
}
__global__ __launch_bounds__(256) void k_final32(const float* __restrict__ in,
                                                 const float* __restrict__ Bc,
                                                 float* __restrict__ out) {
    int bid = blockIdx.x, s = bid & 1, chunk = (bid >> 1) & 31, b = bid >> 6;
    int u = s * 512 + threadIdx.x * 2;
    const float* row  = in  + ((size_t)b * TT + (size_t)chunk * 128) * FF;
    float*       orow = out + ((size_t)b * TT + (size_t)chunk * 128) * UU + u;
    float accx = 0.f, accy = 0.f;
    if (chunk != 0) {
        f2 cv = *reinterpret_cast<const f2*>(Bc + ((size_t)b * 32 + chunk - 1) * UU + u);
        accx = cv.x; accy = cv.y;
    }
#pragma unroll 8
    for (int t = 0; t < 128; ++t) {
        f2 xy = *reinterpret_cast<const f2*>(row + (size_t)t * FF);
        f2 z  = *reinterpret_cast<const f2*>(row + (size_t)t * FF + 2 + u);
        accx = fmaf(xy.y, accx, xy.x * z.x);
        accy = fmaf(xy.y, accy, xy.x * z.y);
        f2 o; o.x = accx; o.y = accy;
        __builtin_nontemporal_store(o, reinterpret_cast<f2*>(orow + (size_t)t * UU));
    }
}

extern "C" void kernel_launch(void* const* d_in, const int* in_sizes, int n_in,
                              void* d_out, int out_size, void* d_ws, size_t ws_size,
                              hipStream_t stream) {
    const float* in  = (const float*)d_in[0];
    float*       out = (float*)d_out;
    char*        ws  = (char*)d_ws;

    // ws layout: flags[NBLK] | counter | pad | Agg[NBLK] | Bc[NBLK][512]
    const size_t off_counter = (size_t)NBLK * 4;                 // 4096
    const size_t off_agg     = off_counter + 128;                // 4224 (16-al)
    const size_t off_bc      = off_agg + (size_t)NBLK * 4;       // 8320 (16-al)
    const size_t need        = off_bc + (size_t)NBLK * 512 * 4;  // ~2.06 MB

    if (ws_size >= need) {
        hipMemsetAsync(ws, 0, off_counter + 4, stream);  // flags + counter
        k_lookback<<<NBLK, 256, 0, stream>>>(
            in, out,
            (int*)ws, (int*)(ws + off_counter),
            (float*)(ws + off_agg), (float*)(ws + off_bc));
    } else {
        float* A  = (float*)ws;           // 8*32 floats
        float* Bc = A + 8 * 32;           // 8*32*1024 floats (~1 MB)
        k_partial32<<<512, 256, 0, stream>>>(in, A, Bc);
        k_scan32<<<16, 256, 0, stream>>>(A, Bc);
        k_final32<<<512, 256, 0, stream>>>(in, Bc, out);
    }
}

// Round 6
// 399.493 us; speedup vs baseline: 1.0947x; 1.0947x over previous
//
#include <hip/hip_runtime.h>

// out[b,t,u] = y[b,t]*out[b,t-1,u] + x[b,t]*z[b,t,u], out[b,-1,u]=0
// in layout: [B][T][F], F=1026: x=col0, y=col1, z=cols 2..1025
//
// Single-pass chunked scan, decoupled look-back, 1 unit/thread:
//  phase 0: stage x_t,y_t of this chunk into LDS (threads 0..63)
//  phase 1: zero-init recurrence, 64 floats of state in REGISTERS,
//           publish (A=prod y, B[u]=state[63]) with release flag
//  phase 2: parallel flag-wait + suffix-product fold of predecessors -> carry
//  phase 3: out[t] = state[t] + carry * prod_{k<=t} y_k   (no input re-read)
// Input read once (134 MB), output written once (134 MB).
// Progress guarantee: vid from atomic counter; block with vid V spins only on
// vids < V, which were claimed by already-started (hence resident) blocks.

#define BB 8
#define TT 4096
#define FF 1026
#define UU 1024
#define NC 64
#define CC 64                    // TT/NC
#define USL 4                    // u-slices of 256 units
#define RPB (BB * USL)           // 32 blocks per chunk-generation
#define NBLK (NC * RPB)          // 2048 blocks

typedef float f2 __attribute__((ext_vector_type(2)));

__global__ __launch_bounds__(256) void k_onepass(const float* __restrict__ in,
                                                 float* __restrict__ out,
                                                 int* __restrict__ flags,   // [NBLK]
                                                 int* __restrict__ counter, // [1]
                                                 float* __restrict__ Agg,   // [NBLK]
                                                 float* __restrict__ Bc) {  // [NBLK][256]
    __shared__ int s_vid;
    __shared__ float s_x[CC], s_y[CC], s_suf[CC];
    if (threadIdx.x == 0) s_vid = atomicAdd(counter, 1);
    __syncthreads();
    const int vid = s_vid;
    const int c    = vid >> 5;        // chunk index (vid-major => preds earlier)
    const int base = vid & 31;        // (b, us)
    const int b    = base >> 2;
    const int us   = base & 3;
    const int tid  = threadIdx.x;
    const int u    = us * 256 + tid;

    const float* row = in + ((size_t)b * TT + (size_t)c * CC) * FF;

    // ---- phase 0: stage x,y ----
    if (tid < CC) {
        f2 xy = *reinterpret_cast<const f2*>(row + (size_t)tid * FF);
        s_x[tid] = xy.x; s_y[tid] = xy.y;
    }
    __syncthreads();

    // ---- phase 1: local scan, state in registers ----
    const float* zp = row + 2 + u;
    float st[CC];
    float acc = 0.f;
#pragma unroll
    for (int t = 0; t < CC; ++t) {
        float z = zp[(size_t)t * FF];
        acc = fmaf(s_y[t], acc, s_x[t] * z);
        st[t] = acc;
    }

    // ---- publish aggregate (release) ----
    Bc[(size_t)vid * 256 + tid] = acc;
    if (tid == 0) {
        float yp = s_y[0];
        for (int t = 1; t < CC; ++t) yp *= s_y[t];
        Agg[vid] = yp;
    }
    __threadfence();
    __syncthreads();
    if (tid == 0)
        __hip_atomic_store(&flags[vid], 1, __ATOMIC_RELEASE, __HIP_MEMORY_SCOPE_AGENT);

    // ---- phase 2: look-back (parallel wait, suffix-product fold) ----
    float carry = 0.f;
    if (c > 0) {
        if (tid < c) {
            while (__hip_atomic_load(&flags[tid * 32 + base], __ATOMIC_ACQUIRE,
                                     __HIP_MEMORY_SCOPE_AGENT) == 0)
                __builtin_amdgcn_s_sleep(1);
        }
        __syncthreads();
        if (tid < c) s_suf[tid] = Agg[tid * 32 + base];
        __syncthreads();
        if (tid == 0) {  // s_suf[j] <- prod_{k=j+1}^{c-1} A_k
            float p = 1.f;
            for (int j = c - 1; j >= 0; --j) { float a = s_suf[j]; s_suf[j] = p; p *= a; }
        }
        __syncthreads();
        for (int j = 0; j < c; ++j)   // independent loads, pipelined
            carry = fmaf(s_suf[j], Bc[(size_t)(j * 32 + base) * 256 + tid], carry);
    }

    // ---- phase 3: apply carry, stream out ----
    float* orow = out + ((size_t)b * TT + (size_t)c * CC) * UU + u;
    float q = carry;
#pragma unroll
    for (int t = 0; t < CC; ++t) {
        q *= s_y[t];
        __builtin_nontemporal_store(st[t] + q, orow + (size_t)t * UU);
    }
}

// ---------------- fallback (round-2 structure, proven 70.5us) ----------------
__global__ __launch_bounds__(256) void k_partial32(const float* __restrict__ in,
                                                   float* __restrict__ A,
                                                   float* __restrict__ Bc) {
    int bid = blockIdx.x, s = bid & 1, chunk = (bid >> 1) & 31, b = bid >> 6;
    int u = s * 512 + threadIdx.x * 2;
    const float* row = in + ((size_t)b * TT + (size_t)chunk * 128) * FF;
    float accx = 0.f, accy = 0.f, yprod = 1.f;
#pragma unroll 8
    for (int t = 0; t < 128; ++t) {
        f2 xy = *reinterpret_cast<const f2*>(row + (size_t)t * FF);
        f2 z  = *reinterpret_cast<const f2*>(row + (size_t)t * FF + 2 + u);
        accx = fmaf(xy.y, accx, xy.x * z.x);
        accy = fmaf(xy.y, accy, xy.x * z.y);
        yprod *= xy.y;
    }
    f2 o; o.x = accx; o.y = accy;
    *reinterpret_cast<f2*>(Bc + ((size_t)b * 32 + chunk) * UU + u) = o;
    if (threadIdx.x == 0 && s == 0) A[b * 32 + chunk] = yprod;
}
__global__ __launch_bounds__(256) void k_scan32(const float* __restrict__ A,
                                                float* __restrict__ Bc) {
    int tid = blockIdx.x * 256 + threadIdx.x;
    int b = tid / 512, u = (tid % 512) * 2;
    float cx = 0.f, cy = 0.f;
#pragma unroll
    for (int c = 0; c < 32; ++c) {
        float a = A[b * 32 + c];
        f2* p = reinterpret_cast<f2*>(Bc + ((size_t)b * 32 + c) * UU + u);
        f2 bv = *p;
        cx = fmaf(a, cx, bv.x); cy = fmaf(a, cy, bv.y);
        f2 o; o.x = cx; o.y = cy; *p = o;
    }
}
__global__ __launch_bounds__(256) void k_final32(const float* __restrict__ in,
                                                 const float* __restrict__ Bc,
                                                 float* __restrict__ out) {
    int bid = blockIdx.x, s = bid & 1, chunk = (bid >> 1) & 31, b = bid >> 6;
    int u = s * 512 + threadIdx.x * 2;
    const float* row  = in  + ((size_t)b * TT + (size_t)chunk * 128) * FF;
    float*       orow = out + ((size_t)b * TT + (size_t)chunk * 128) * UU + u;
    float accx = 0.f, accy = 0.f;
    if (chunk != 0) {
        f2 cv = *reinterpret_cast<const f2*>(Bc + ((size_t)b * 32 + chunk - 1) * UU + u);
        accx = cv.x; accy = cv.y;
    }
#pragma unroll 8
    for (int t = 0; t < 128; ++t) {
        f2 xy = *reinterpret_cast<const f2*>(row + (size_t)t * FF);
        f2 z  = *reinterpret_cast<const f2*>(row + (size_t)t * FF + 2 + u);
        accx = fmaf(xy.y, accx, xy.x * z.x);
        accy = fmaf(xy.y, accy, xy.x * z.y);
        f2 o; o.x = accx; o.y = accy;
        __builtin_nontemporal_store(o, reinterpret_cast<f2*>(orow + (size_t)t * UU));
    }
}

extern "C" void kernel_launch(void* const* d_in, const int* in_sizes, int n_in,
                              void* d_out, int out_size, void* d_ws, size_t ws_size,
                              hipStream_t stream) {
    const float* in  = (const float*)d_in[0];
    float*       out = (float*)d_out;
    char*        ws  = (char*)d_ws;

    // ws: flags[NBLK] | counter(+pad) | Agg[NBLK] | Bc[NBLK][256]
    const size_t off_counter = (size_t)NBLK * 4;                  // 8192
    const size_t off_agg     = off_counter + 128;                 // 8320
    const size_t off_bc      = off_agg + (size_t)NBLK * 4;        // 16512
    const size_t need        = off_bc + (size_t)NBLK * 256 * 4;   // ~2.02 MB

    if (ws_size >= need) {
        hipMemsetAsync(ws, 0, off_counter + 4, stream);  // flags + counter
        k_onepass<<<NBLK, 256, 0, stream>>>(
            in, out,
            (int*)ws, (int*)(ws + off_counter),
            (float*)(ws + off_agg), (float*)(ws + off_bc));
    } else {
        float* A  = (float*)ws;
        float* Bc = A + 8 * 32;
        k_partial32<<<512, 256, 0, stream>>>(in, A, Bc);
        k_scan32<<<16, 256, 0, stream>>>(A, Bc);
        k_final32<<<512, 256, 0, stream>>>(in, Bc, out);
    }
}

// Round 7
// 393.354 us; speedup vs baseline: 1.1117x; 1.0156x over previous
//
#include <hip/hip_runtime.h>

// out[b,t,u] = y[b,t]*out[b,t-1,u] + x[b,t]*z[b,t,u], out[b,-1,u]=0
// in layout: [B][T][F], F=1026: x=col0, y=col1, z=cols 2..1025
//
// Single-pass chunked scan, decoupled look-back, 1 unit/thread.
// KEY FIX vs R6: phase-1/3 loops are template-recursive so every st[I]
// access is a CONSTANT-index GEP at IR-gen time -> SROA promotes the
// 64-float state array to registers (R4/R6 spilled it to scratch: VGPR=52,
// 84 MB scratch FETCH, 530us).
//
// Progress guarantee: vid from atomic counter; block with vid V spins only
// on vids < V, claimed by already-started (hence resident) blocks.

#define BB 8
#define TT 4096
#define FF 1026
#define UU 1024
#define NC 64
#define CC 64                    // TT/NC
#define USL 4                    // u-slices of 256 units
#define RPB (BB * USL)           // 32 blocks per chunk-generation
#define NBLK (NC * RPB)          // 2048 blocks

typedef float f2 __attribute__((ext_vector_type(2)));

// ---- constant-index unrolled phase 1: local scan, state into st[] ----
template <int T>
__device__ __forceinline__ void scan_steps(float (&st)[CC], float& acc,
                                           const float* __restrict__ zp,
                                           const float* __restrict__ sx,
                                           const float* __restrict__ sy) {
    if constexpr (T < CC) {
        float z = zp[(size_t)T * FF];
        acc = fmaf(sy[T], acc, sx[T] * z);
        st[T] = acc;
        scan_steps<T + 1>(st, acc, zp, sx, sy);
    }
}

// ---- constant-index unrolled phase 3: apply carry, stream out ----
template <int T>
__device__ __forceinline__ void out_steps(const float (&st)[CC], float& q,
                                          const float* __restrict__ sy,
                                          float* __restrict__ orow) {
    if constexpr (T < CC) {
        q *= sy[T];
        __builtin_nontemporal_store(st[T] + q, orow + (size_t)T * UU);
        out_steps<T + 1>(st, q, sy, orow);
    }
}

__global__ __launch_bounds__(256) void k_onepass(const float* __restrict__ in,
                                                 float* __restrict__ out,
                                                 int* __restrict__ flags,   // [NBLK]
                                                 int* __restrict__ counter, // [1]
                                                 float* __restrict__ Agg,   // [NBLK]
                                                 float* __restrict__ Bc) {  // [NBLK][256]
    __shared__ int s_vid;
    __shared__ float s_x[CC], s_y[CC], s_suf[CC];
    if (threadIdx.x == 0) s_vid = atomicAdd(counter, 1);
    __syncthreads();
    const int vid = s_vid;
    const int c    = vid >> 5;        // chunk index (vid-major => preds earlier)
    const int base = vid & 31;        // (b, us)
    const int b    = base >> 2;
    const int us   = base & 3;
    const int tid  = threadIdx.x;
    const int u    = us * 256 + tid;

    const float* row = in + ((size_t)b * TT + (size_t)c * CC) * FF;

    // ---- phase 0: stage x,y ----
    if (tid < CC) {
        f2 xy = *reinterpret_cast<const f2*>(row + (size_t)tid * FF);
        s_x[tid] = xy.x; s_y[tid] = xy.y;
    }
    __syncthreads();

    // ---- phase 1: local scan, state in registers ----
    float st[CC];
    float acc = 0.f;
    scan_steps<0>(st, acc, row + 2 + u, s_x, s_y);

    // ---- publish aggregate (release) ----
    Bc[(size_t)vid * 256 + tid] = acc;
    if (tid == 0) {
        float yp = s_y[0];
        for (int t = 1; t < CC; ++t) yp *= s_y[t];
        Agg[vid] = yp;
    }
    __threadfence();
    __syncthreads();
    if (tid == 0)
        __hip_atomic_store(&flags[vid], 1, __ATOMIC_RELEASE, __HIP_MEMORY_SCOPE_AGENT);

    // ---- phase 2: look-back (parallel wait, suffix-product fold) ----
    float carry = 0.f;
    if (c > 0) {
        if (tid < c) {
            while (__hip_atomic_load(&flags[tid * 32 + base], __ATOMIC_ACQUIRE,
                                     __HIP_MEMORY_SCOPE_AGENT) == 0)
                __builtin_amdgcn_s_sleep(1);
        }
        __syncthreads();
        if (tid < c) s_suf[tid] = Agg[tid * 32 + base];
        __syncthreads();
        if (tid == 0) {  // s_suf[j] <- prod_{k=j+1}^{c-1} A_k
            float p = 1.f;
            for (int j = c - 1; j >= 0; --j) { float a = s_suf[j]; s_suf[j] = p; p *= a; }
        }
        __syncthreads();
        for (int j = 0; j < c; ++j)   // independent loads, pipelined
            carry = fmaf(s_suf[j], Bc[(size_t)(j * 32 + base) * 256 + tid], carry);
    }

    // ---- phase 3: apply carry, stream out ----
    float* orow = out + ((size_t)b * TT + (size_t)c * CC) * UU + u;
    float q = carry;
    out_steps<0>(st, q, s_y, orow);
}

// ---------------- fallback (round-2 structure, proven 70.5us) ----------------
__global__ __launch_bounds__(256) void k_partial32(const float* __restrict__ in,
                                                   float* __restrict__ A,
                                                   float* __restrict__ Bc) {
    int bid = blockIdx.x, s = bid & 1, chunk = (bid >> 1) & 31, b = bid >> 6;
    int u = s * 512 + threadIdx.x * 2;
    const float* row = in + ((size_t)b * TT + (size_t)chunk * 128) * FF;
    float accx = 0.f, accy = 0.f, yprod = 1.f;
#pragma unroll 8
    for (int t = 0; t < 128; ++t) {
        f2 xy = *reinterpret_cast<const f2*>(row + (size_t)t * FF);
        f2 z  = *reinterpret_cast<const f2*>(row + (size_t)t * FF + 2 + u);
        accx = fmaf(xy.y, accx, xy.x * z.x);
        accy = fmaf(xy.y, accy, xy.x * z.y);
        yprod *= xy.y;
    }
    f2 o; o.x = accx; o.y = accy;
    *reinterpret_cast<f2*>(Bc + ((size_t)b * 32 + chunk) * UU + u) = o;
    if (threadIdx.x == 0 && s == 0) A[b * 32 + chunk] = yprod;
}
__global__ __launch_bounds__(256) void k_scan32(const float* __restrict__ A,
                                                float* __restrict__ Bc) {
    int tid = blockIdx.x * 256 + threadIdx.x;
    int b = tid / 512, u = (tid % 512) * 2;
    float cx = 0.f, cy = 0.f;
#pragma unroll
    for (int c = 0; c < 32; ++c) {
        float a = A[b * 32 + c];
        f2* p = reinterpret_cast<f2*>(Bc + ((size_t)b * 32 + c) * UU + u);
        f2 bv = *p;
        cx = fmaf(a, cx, bv.x); cy = fmaf(a, cy, bv.y);
        f2 o; o.x = cx; o.y = cy; *p = o;
    }
}
__global__ __launch_bounds__(256) void k_final32(const float* __restrict__ in,
                                                 const float* __restrict__ Bc,
                                                 float* __restrict__ out) {
    int bid = blockIdx.x, s = bid & 1, chunk = (bid >> 1) & 31, b = bid >> 6;
    int u = s * 512 + threadIdx.x * 2;
    const float* row  = in  + ((size_t)b * TT + (size_t)chunk * 128) * FF;
    float*       orow = out + ((size_t)b * TT + (size_t)chunk * 128) * UU + u;
    float accx = 0.f, accy = 0.f;
    if (chunk != 0) {
        f2 cv = *reinterpret_cast<const f2*>(Bc + ((size_t)b * 32 + chunk - 1) * UU + u);
        accx = cv.x; accy = cv.y;
    }
#pragma unroll 8
    for (int t = 0; t < 128; ++t) {
        f2 xy = *reinterpret_cast<const f2*>(row + (size_t)t * FF);
        f2 z  = *reinterpret_cast<const f2*>(row + (size_t)t * FF + 2 + u);
        accx = fmaf(xy.y, accx, xy.x * z.x);
        accy = fmaf(xy.y, accy, xy.x * z.y);
        f2 o; o.x = accx; o.y = accy;
        __builtin_nontemporal_store(o, reinterpret_cast<f2*>(orow + (size_t)t * UU));
    }
}

extern "C" void kernel_launch(void* const* d_in, const int* in_sizes, int n_in,
                              void* d_out, int out_size, void* d_ws, size_t ws_size,
                              hipStream_t stream) {
    const float* in  = (const float*)d_in[0];
    float*       out = (float*)d_out;
    char*        ws  = (char*)d_ws;

    // ws: flags[NBLK] | counter(+pad) | Agg[NBLK] | Bc[NBLK][256]
    const size_t off_counter = (size_t)NBLK * 4;                  // 8192
    const size_t off_agg     = off_counter + 128;                 // 8320
    const size_t off_bc      = off_agg + (size_t)NBLK * 4;        // 16512
    const size_t need        = off_bc + (size_t)NBLK * 256 * 4;   // ~2.02 MB

    if (ws_size >= need) {
        hipMemsetAsync(ws, 0, off_counter + 4, stream);  // flags + counter
        k_onepass<<<NBLK, 256, 0, stream>>>(
            in, out,
            (int*)ws, (int*)(ws + off_counter),
            (float*)(ws + off_agg), (float*)(ws + off_bc));
    } else {
        float* A  = (float*)ws;
        float* Bc = A + 8 * 32;
        k_partial32<<<512, 256, 0, stream>>>(in, A, Bc);
        k_scan32<<<16, 256, 0, stream>>>(A, Bc);
        k_final32<<<512, 256, 0, stream>>>(in, Bc, out);
    }
}

// Round 8
// 391.479 us; speedup vs baseline: 1.1171x; 1.0048x over previous
//
#include <hip/hip_runtime.h>

// out[b,t,u] = y[b,t]*out[b,t-1,u] + x[b,t]*z[b,t,u], out[b,-1,u]=0
// in layout: [B][T][F], F=1026: x=col0, y=col1, z=cols 2..1025
//
// Single-pass chunked scan, decoupled look-back, 1 unit/thread.
// KEY FIX vs R7: chunk state is a single ext_vector_type(64) SSA VALUE
// (not a float[64] alloca). mem2reg promotes whole-vector load/store
// unconditionally, and template-recursion keeps every element index
// compile-time constant -> no dynamic extract -> no scratch.
// (R4/R6/R7 all spilled the state array: VGPR=52, latency-bound, ~520us.)
//
// Progress guarantee: vid from atomic counter; block with vid V spins only
// on vids < V, claimed by already-started (hence resident-or-finished) blocks.

#define BB 8
#define TT 4096
#define FF 1026
#define UU 1024
#define NC 64
#define CC 64                    // TT/NC
#define USL 4                    // u-slices of 256 units
#define RPB (BB * USL)           // 32 blocks per chunk-generation
#define NBLK (NC * RPB)          // 2048 blocks

typedef float f2  __attribute__((ext_vector_type(2)));
typedef float v64 __attribute__((ext_vector_type(64)));   // chunk state, SSA value

// ---- phase 1: local scan; st[T] element index is a template constant ----
template <int T>
__device__ __forceinline__ void scan_steps(v64& st, float& acc,
                                           const float* __restrict__ zp,
                                           const float* __restrict__ sx,
                                           const float* __restrict__ sy) {
    if constexpr (T < CC) {
        float z = zp[(size_t)T * FF];
        acc = fmaf(sy[T], acc, sx[T] * z);
        st[T] = acc;
        scan_steps<T + 1>(st, acc, zp, sx, sy);
    }
}

// ---- phase 3: apply carry, stream out ----
template <int T>
__device__ __forceinline__ void out_steps(const v64& st, float& q,
                                          const float* __restrict__ sy,
                                          float* __restrict__ orow) {
    if constexpr (T < CC) {
        q *= sy[T];
        __builtin_nontemporal_store(st[T] + q, orow + (size_t)T * UU);
        out_steps<T + 1>(st, q, sy, orow);
    }
}

__global__ __launch_bounds__(256) void k_onepass(const float* __restrict__ in,
                                                 float* __restrict__ out,
                                                 int* __restrict__ flags,   // [NBLK]
                                                 int* __restrict__ counter, // [1]
                                                 float* __restrict__ Agg,   // [NBLK]
                                                 float* __restrict__ Bc) {  // [NBLK][256]
    __shared__ int s_vid;
    __shared__ float s_x[CC], s_y[CC], s_suf[CC];
    if (threadIdx.x == 0) s_vid = atomicAdd(counter, 1);
    __syncthreads();
    const int vid = s_vid;
    const int c    = vid >> 5;        // chunk index (vid-major => preds earlier)
    const int base = vid & 31;        // (b, us)
    const int b    = base >> 2;
    const int us   = base & 3;
    const int tid  = threadIdx.x;
    const int u    = us * 256 + tid;

    const float* row = in + ((size_t)b * TT + (size_t)c * CC) * FF;

    // ---- phase 0: stage x,y ----
    if (tid < CC) {
        f2 xy = *reinterpret_cast<const f2*>(row + (size_t)tid * FF);
        s_x[tid] = xy.x; s_y[tid] = xy.y;
    }
    __syncthreads();

    // ---- phase 1: local scan, state in a 64-wide register vector ----
    v64 st;
    float acc = 0.f;
    scan_steps<0>(st, acc, row + 2 + u, s_x, s_y);

    // ---- publish aggregate (release) ----
    Bc[(size_t)vid * 256 + tid] = acc;
    if (tid == 0) {
        float yp = s_y[0];
        for (int t = 1; t < CC; ++t) yp *= s_y[t];
        Agg[vid] = yp;
    }
    __threadfence();
    __syncthreads();
    if (tid == 0)
        __hip_atomic_store(&flags[vid], 1, __ATOMIC_RELEASE, __HIP_MEMORY_SCOPE_AGENT);

    // ---- phase 2: look-back (parallel wait, suffix-product fold) ----
    float carry = 0.f;
    if (c > 0) {
        if (tid < c) {
            while (__hip_atomic_load(&flags[tid * 32 + base], __ATOMIC_ACQUIRE,
                                     __HIP_MEMORY_SCOPE_AGENT) == 0)
                __builtin_amdgcn_s_sleep(1);
        }
        __syncthreads();
        if (tid < c) s_suf[tid] = Agg[tid * 32 + base];
        __syncthreads();
        if (tid == 0) {  // s_suf[j] <- prod_{k=j+1}^{c-1} A_k
            float p = 1.f;
            for (int j = c - 1; j >= 0; --j) { float a = s_suf[j]; s_suf[j] = p; p *= a; }
        }
        __syncthreads();
        for (int j = 0; j < c; ++j)   // independent loads, pipelined
            carry = fmaf(s_suf[j], Bc[(size_t)(j * 32 + base) * 256 + tid], carry);
    }

    // ---- phase 3: apply carry, stream out ----
    float* orow = out + ((size_t)b * TT + (size_t)c * CC) * UU + u;
    float q = carry;
    out_steps<0>(st, q, s_y, orow);
}

// ---------------- fallback (round-2 structure, proven 70.5us) ----------------
__global__ __launch_bounds__(256) void k_partial32(const float* __restrict__ in,
                                                   float* __restrict__ A,
                                                   float* __restrict__ Bc) {
    int bid = blockIdx.x, s = bid & 1, chunk = (bid >> 1) & 31, b = bid >> 6;
    int u = s * 512 + threadIdx.x * 2;
    const float* row = in + ((size_t)b * TT + (size_t)chunk * 128) * FF;
    float accx = 0.f, accy = 0.f, yprod = 1.f;
#pragma unroll 8
    for (int t = 0; t < 128; ++t) {
        f2 xy = *reinterpret_cast<const f2*>(row + (size_t)t * FF);
        f2 z  = *reinterpret_cast<const f2*>(row + (size_t)t * FF + 2 + u);
        accx = fmaf(xy.y, accx, xy.x * z.x);
        accy = fmaf(xy.y, accy, xy.x * z.y);
        yprod *= xy.y;
    }
    f2 o; o.x = accx; o.y = accy;
    *reinterpret_cast<f2*>(Bc + ((size_t)b * 32 + chunk) * UU + u) = o;
    if (threadIdx.x == 0 && s == 0) A[b * 32 + chunk] = yprod;
}
__global__ __launch_bounds__(256) void k_scan32(const float* __restrict__ A,
                                                float* __restrict__ Bc) {
    int tid = blockIdx.x * 256 + threadIdx.x;
    int b = tid / 512, u = (tid % 512) * 2;
    float cx = 0.f, cy = 0.f;
#pragma unroll
    for (int c = 0; c < 32; ++c) {
        float a = A[b * 32 + c];
        f2* p = reinterpret_cast<f2*>(Bc + ((size_t)b * 32 + c) * UU + u);
        f2 bv = *p;
        cx = fmaf(a, cx, bv.x); cy = fmaf(a, cy, bv.y);
        f2 o; o.x = cx; o.y = cy; *p = o;
    }
}
__global__ __launch_bounds__(256) void k_final32(const float* __restrict__ in,
                                                 const float* __restrict__ Bc,
                                                 float* __restrict__ out) {
    int bid = blockIdx.x, s = bid & 1, chunk = (bid >> 1) & 31, b = bid >> 6;
    int u = s * 512 + threadIdx.x * 2;
    const float* row  = in  + ((size_t)b * TT + (size_t)chunk * 128) * FF;
    float*       orow = out + ((size_t)b * TT + (size_t)chunk * 128) * UU + u;
    float accx = 0.f, accy = 0.f;
    if (chunk != 0) {
        f2 cv = *reinterpret_cast<const f2*>(Bc + ((size_t)b * 32 + chunk - 1) * UU + u);
        accx = cv.x; accy = cv.y;
    }
#pragma unroll 8
    for (int t = 0; t < 128; ++t) {
        f2 xy = *reinterpret_cast<const f2*>(row + (size_t)t * FF);
        f2 z  = *reinterpret_cast<const f2*>(row + (size_t)t * FF + 2 + u);
        accx = fmaf(xy.y, accx, xy.x * z.x);
        accy = fmaf(xy.y, accy, xy.x * z.y);
        f2 o; o.x = accx; o.y = accy;
        __builtin_nontemporal_store(o, reinterpret_cast<f2*>(orow + (size_t)t * UU));
    }
}

extern "C" void kernel_launch(void* const* d_in, const int* in_sizes, int n_in,
                              void* d_out, int out_size, void* d_ws, size_t ws_size,
                              hipStream_t stream) {
    const float* in  = (const float*)d_in[0];
    float*       out = (float*)d_out;
    char*        ws  = (char*)d_ws;

    // ws: flags[NBLK] | counter(+pad) | Agg[NBLK] | Bc[NBLK][256]
    const size_t off_counter = (size_t)NBLK * 4;                  // 8192
    const size_t off_agg     = off_counter + 128;                 // 8320
    const size_t off_bc      = off_agg + (size_t)NBLK * 4;        // 16512
    const size_t need        = off_bc + (size_t)NBLK * 256 * 4;   // ~2.02 MB

    if (ws_size >= need) {
        hipMemsetAsync(ws, 0, off_counter + 4, stream);  // flags + counter
        k_onepass<<<NBLK, 256, 0, stream>>>(
            in, out,
            (int*)ws, (int*)(ws + off_counter),
            (float*)(ws + off_agg), (float*)(ws + off_bc));
    } else {
        float* A  = (float*)ws;
        float* Bc = A + 8 * 32;
        k_partial32<<<512, 256, 0, stream>>>(in, A, Bc);
        k_scan32<<<16, 256, 0, stream>>>(A, Bc);
        k_final32<<<512, 256, 0, stream>>>(in, Bc, out);
    }
}